// Round 4
// baseline (11674.905 us; speedup 1.0000x reference)
//
#include <hip/hip_runtime.h>
#include <cmath>

// ---------------------------------------------------------------------------
// BertBiLSTMCRF round 4: LDS-resident recurrent weights, race-free flag sync.
//   lstm_scan: 64 blocks = 2 dir x 32 slices; each block owns 8 hidden units
//   (32 gate cols, 32KB weights in LDS, loaded once). Per step:
//     gates(LDS) -> c/h update -> h slice to hG[parity] -> release fence+add
//     -> acquire poll (TIMEOUT-guarded, converts any hang into wrong answer)
//     -> invalidate fence -> reload full h. hG double-buffered by step parity:
//   with per-step counters this is race-free (a block writes buf[s&1] only
//   after ctr[s-1] completed => all blocks finished reading it at step s-2).
// ---------------------------------------------------------------------------

#define NB 32
#define NT 512
#define ND 768
#define NH 256
#define NG 1024   // 4*NH
#define NC 2048   // 2*NG
#define NL 9
#define NHC 512   // 2*NH
#define PPD 32    // blocks (slices) per direction
#define HPAD 260  // padded row stride for hS
#define NBUF (2 * NB * NH)   // one parity buffer: [2 dirs][32 b][256]

static const size_t OFF_WIHT  = 0;                       // 1572864 floats
static const size_t OFF_WHHT  = 1572864;                 // 524288
static const size_t OFF_XPART = 2097152;                 // 33554432
static const size_t OFF_HCAT  = 35651584;                // 8388608
static const size_t OFF_HG    = 44040192;                // 2*16384 = 32768
static const size_t OFF_CTR   = 44072960;                // 1024 ints
// total ~44,073,984 floats = 176.3 MB

// ---------------------------------------------------------------- prep ------
__global__ void prep(const float* __restrict__ wihf, const float* __restrict__ wihb,
                     const float* __restrict__ whhf, const float* __restrict__ whhb,
                     float* __restrict__ w_ihT, float* __restrict__ w_hhT,
                     float* __restrict__ d_loss, int* __restrict__ ctr) {
  int idx = blockIdx.x * 256 + threadIdx.x;
  if (idx == 0) d_loss[0] = 0.f;
  if (idx < 1024) ctr[idx] = 0;          // 2*512 step counters
  if (idx < 1572864) {
    int k = idx >> 11;
    int c = idx & 2047;
    int d = c >> 10;
    int j = c & 1023;
    w_ihT[idx] = d ? wihb[j * ND + k] : wihf[j * ND + k];
  } else {
    int i2 = idx - 1572864;
    int d = i2 >> 18;
    int r = i2 & 262143;
    int k = r >> 10;
    int j = r & 1023;
    w_hhT[i2] = d ? whhb[j * NH + k] : whhf[j * NH + k];
  }
}

// -------------------------------------------------------------- gemm_x ------
__global__ __launch_bounds__(256, 2)
void gemm_x(const float* __restrict__ x, const float* __restrict__ wT,
            const float* __restrict__ bf, const float* __restrict__ bb,
            float* __restrict__ xpart) {
  __shared__ float As[8][128];
  __shared__ float Bs[8][128];
  const int tid = threadIdx.x;
  const int tx = tid & 15, ty = tid >> 4;
  const int r0 = blockIdx.y * 128, c0 = blockIdx.x * 128;

  float acc[8][8] = {};

  const int arow = tid >> 1;
  const int akq  = (tid & 1) * 4;
  const int rA = r0 + arow;
  const float* aptr = x + ((size_t)((rA & 31) * NT + (rA >> 5)) * ND) + akq;
  const int bk = tid >> 5;
  const int bc = (tid & 31) * 4;
  const float* bptr = wT + (size_t)bk * NC + c0 + bc;

  for (int k0 = 0; k0 < ND; k0 += 8) {
    float4 av = *(const float4*)(aptr + k0);
    float4 bv = *(const float4*)(bptr + (size_t)k0 * NC);
    __syncthreads();
    As[akq + 0][arow] = av.x;
    As[akq + 1][arow] = av.y;
    As[akq + 2][arow] = av.z;
    As[akq + 3][arow] = av.w;
    *(float4*)&Bs[bk][bc] = bv;
    __syncthreads();
#pragma unroll
    for (int k = 0; k < 8; ++k) {
      float4 a0 = *(const float4*)&As[k][ty * 8];
      float4 a1 = *(const float4*)&As[k][ty * 8 + 4];
      float4 b0 = *(const float4*)&Bs[k][tx * 8];
      float4 b1 = *(const float4*)&Bs[k][tx * 8 + 4];
      float am[8] = {a0.x, a0.y, a0.z, a0.w, a1.x, a1.y, a1.z, a1.w};
      float bm[8] = {b0.x, b0.y, b0.z, b0.w, b1.x, b1.y, b1.z, b1.w};
#pragma unroll
      for (int i = 0; i < 8; ++i)
#pragma unroll
        for (int j = 0; j < 8; ++j) acc[i][j] += am[i] * bm[j];
    }
  }

  const int cbase = c0 + tx * 8;
  float bias[8];
#pragma unroll
  for (int j = 0; j < 8; ++j) {
    int c = cbase + j;
    bias[j] = (c < NG) ? bf[c] : bb[c - NG];
  }
#pragma unroll
  for (int i = 0; i < 8; ++i) {
    int r = r0 + ty * 8 + i;
    float4 v0 = {acc[i][0] + bias[0], acc[i][1] + bias[1],
                 acc[i][2] + bias[2], acc[i][3] + bias[3]};
    float4 v1 = {acc[i][4] + bias[4], acc[i][5] + bias[5],
                 acc[i][6] + bias[6], acc[i][7] + bias[7]};
    *(float4*)(xpart + (size_t)r * NC + cbase) = v0;
    *(float4*)(xpart + (size_t)r * NC + cbase + 4) = v1;
  }
}

// ------------------------------------------------------------ lstm_scan -----
__global__ __launch_bounds__(256, 1)
void lstm_scan(const float* __restrict__ whhT, const float* __restrict__ xpart,
               float* __restrict__ hcat, float* __restrict__ hG,
               int* __restrict__ ctr) {
  __shared__ float wS[256 * 32];      // [k][l]
  __shared__ float hS[32 * HPAD];     // [b][k], padded
  __shared__ float gS[32 * 36];       // [b][l], padded
  const int tid = threadIdx.x;
  const int d = blockIdx.x >> 5;
  const int m = blockIdx.x & 31;

  // one-time weight slice load: wS[k][l], l=g*8+u -> col g*256+m*8+u
  const float* wsrc = whhT + (size_t)d * NH * NG;
  for (int it = 0; it < 32; ++it) {
    int i = it * 256 + tid;
    int k = i >> 5, l = i & 31;
    int g = l >> 3, u2 = l & 7;
    wS[k * 32 + l] = wsrc[(size_t)k * NG + g * 256 + m * 8 + u2];
  }
  for (int i = tid; i < 32 * HPAD; i += 256) hS[i] = 0.f;
  __syncthreads();

  const int b = tid >> 3;
  const int cg = tid & 7;
  const int u = tid & 7;
  const int l0 = cg * 4;
  const int g4 = l0 >> 3, u04 = l0 & 7;
  const int col4 = g4 * 256 + m * 8 + u04;   // 4 consecutive gate cols
  int* ctrd = ctr + d * NT;

  float c = 0.f;
  for (int s = 0; s < NT; ++s) {
    const int t = d ? (NT - 1 - s) : s;
    float4 xv = *(const float4*)(xpart + ((size_t)(t * NB + b) * NC) + d * NG + col4);
    float4 acc = {0.f, 0.f, 0.f, 0.f};
    const float* hrow = &hS[b * HPAD];
    for (int k0 = 0; k0 < NH; k0 += 4) {
      float4 hv = *(const float4*)(hrow + k0);
      {
        float4 wv = *(const float4*)(&wS[(k0 + 0) * 32 + l0]);
        acc.x += hv.x * wv.x; acc.y += hv.x * wv.y; acc.z += hv.x * wv.z; acc.w += hv.x * wv.w;
      }
      {
        float4 wv = *(const float4*)(&wS[(k0 + 1) * 32 + l0]);
        acc.x += hv.y * wv.x; acc.y += hv.y * wv.y; acc.z += hv.y * wv.z; acc.w += hv.y * wv.w;
      }
      {
        float4 wv = *(const float4*)(&wS[(k0 + 2) * 32 + l0]);
        acc.x += hv.z * wv.x; acc.y += hv.z * wv.y; acc.z += hv.z * wv.z; acc.w += hv.z * wv.w;
      }
      {
        float4 wv = *(const float4*)(&wS[(k0 + 3) * 32 + l0]);
        acc.x += hv.w * wv.x; acc.y += hv.w * wv.y; acc.z += hv.w * wv.z; acc.w += hv.w * wv.w;
      }
    }
    acc.x += xv.x; acc.y += xv.y; acc.z += xv.z; acc.w += xv.w;
    *(float4*)(&gS[b * 36 + l0]) = acc;
    __syncthreads();

    // c/h update for (b, unit m*8+u)
    float gi = gS[b * 36 + u];
    float gf = gS[b * 36 + 8 + u];
    float gg = gS[b * 36 + 16 + u];
    float go = gS[b * 36 + 24 + u];
    float ii = 1.f / (1.f + expf(-gi));
    float ff = 1.f / (1.f + expf(-gf));
    float tg = tanhf(gg);
    float oo = 1.f / (1.f + expf(-go));
    c = ff * c + ii * tg;
    float h = oo * tanhf(c);
    hcat[((size_t)(b * NT + t)) * NHC + d * NH + m * 8 + u] = h;

    if (s < NT - 1) {
      float* buf = hG + ((s & 1) ? NBUF : 0) + d * (NB * NH);
      buf[b * NH + m * 8 + u] = h;
      __threadfence();                 // release: drain + L2 writeback (agent)
      __syncthreads();
      if (tid == 0)
        __hip_atomic_fetch_add(&ctrd[s], 1, __ATOMIC_RELEASE,
                               __HIP_MEMORY_SCOPE_AGENT);
      if ((tid & 63) == 0) {
        long long t0 = wall_clock64();
        while (__hip_atomic_load(&ctrd[s], __ATOMIC_ACQUIRE,
                                 __HIP_MEMORY_SCOPE_AGENT) < PPD) {
          __builtin_amdgcn_s_sleep(1);
          if (wall_clock64() - t0 > 5000000LL) break;  // ~50ms hang guard
        }
      }
      __syncthreads();
      __threadfence();                 // acquire: invalidate stale cache lines
      for (int i = tid; i < 2048; i += 256) {
        float4 v = *(const float4*)(buf + i * 4);
        int bb = i >> 6, kk = (i & 63) * 4;
        *(float4*)(&hS[bb * HPAD + kk]) = v;
      }
      __syncthreads();
    }
  }
}

// ------------------------------------------------------------ emissions -----
__global__ void emissions(const float* __restrict__ hcat, const float* __restrict__ wtag,
                          const float* __restrict__ btag, float* __restrict__ em) {
  __shared__ float wS[NL * NHC];
  const int tid = threadIdx.x;
  for (int i = tid; i < NL * NHC; i += 256) wS[i] = wtag[i];
  __syncthreads();
  const int w = tid >> 6, l = tid & 63;
  const int r = blockIdx.x * 4 + w;
  const float* hp = hcat + (size_t)r * NHC;
  float acc[NL] = {};
#pragma unroll
  for (int rep = 0; rep < 8; ++rep) {
    float hv = hp[l + rep * 64];
#pragma unroll
    for (int j = 0; j < NL; ++j) acc[j] += hv * wS[j * NHC + l + rep * 64];
  }
#pragma unroll
  for (int j = 0; j < NL; ++j) {
#pragma unroll
    for (int off = 32; off; off >>= 1) acc[j] += __shfl_xor(acc[j], off, 64);
  }
  if (l == 0) {
#pragma unroll
    for (int j = 0; j < NL; ++j) em[(size_t)r * NL + j] = acc[j] + btag[j];
  }
}

// -------------------------------------------------------------- crf_fwd -----
__global__ void crf_fwd(const float* __restrict__ em, const int* __restrict__ mask,
                        const int* __restrict__ labels, const float* __restrict__ start,
                        const float* __restrict__ endt, const float* __restrict__ trans,
                        float* __restrict__ d_loss) {
  __shared__ float emS[NT * NL];
  __shared__ float maskS[NT];
  __shared__ int lblS[NT];
  const int b = blockIdx.x;
  const int tid = threadIdx.x;
  for (int i = tid; i < NT * NL; i += 64) emS[i] = em[(size_t)b * NT * NL + i];
  for (int i = tid; i < NT; i += 64) {
    maskS[i] = (float)mask[b * NT + i];
    int lb = labels[b * NT + i];
    lblS[i] = (lb == -100) ? 0 : lb;
  }
  __syncthreads();

  float part = 0.f, msum = 0.f;
  for (int t = tid; t < NT; t += 64) {
    msum += maskS[t];
    if (t >= 1)
      part += (trans[lblS[t - 1] * NL + lblS[t]] + emS[t * NL + lblS[t]]) * maskS[t];
  }
#pragma unroll
  for (int off = 32; off; off >>= 1) {
    part += __shfl_xor(part, off, 64);
    msum += __shfl_xor(msum, off, 64);
  }

  const int j = tid >> 2, q = tid & 3;
  const bool leader = (q == 0) && (j < NL);
  float tr0 = 0.f, tr1 = 0.f, tr2 = -1e30f;
  float score = 0.f;
  if (tid < 36) {
    tr0 = trans[q * NL + j];
    tr1 = trans[(q + 4) * NL + j];
    if (q == 0) tr2 = trans[8 * NL + j];
    if (leader) score = start[j] + emS[j];
  }
  for (int t = 1; t < NT; ++t) {
    float s0 = __shfl(score, q * 4, 64);
    float s1 = __shfl(score, (q + 4) * 4, 64);
    float s2 = __shfl(score, 32, 64);
    float v0 = s0 + tr0, v1 = s1 + tr1;
    float v2 = (q == 0) ? (s2 + tr2) : -1e30f;
    float m = fmaxf(fmaxf(v0, v1), v2);
    m = fmaxf(m, __shfl_xor(m, 1, 4));
    m = fmaxf(m, __shfl_xor(m, 2, 4));
    float e = expf(v0 - m) + expf(v1 - m) + ((q == 0) ? expf(v2 - m) : 0.f);
    e += __shfl_xor(e, 1, 4);
    e += __shfl_xor(e, 2, 4);
    if (leader) {
      float nxt = m + logf(e) + emS[t * NL + j];
      score = (maskS[t] > 0.f) ? nxt : score;
    }
  }
  float vs[NL];
  float mx = -1e30f;
#pragma unroll
  for (int jj = 0; jj < NL; ++jj) {
    float sj = __shfl(score, jj * 4, 64) + endt[jj];
    vs[jj] = sj;
    mx = fmaxf(mx, sj);
  }
  float se = 0.f;
#pragma unroll
  for (int jj = 0; jj < NL; ++jj) se += expf(vs[jj] - mx);
  float denom = mx + logf(se);
  if (tid == 0) {
    int li = (int)(msum - 0.5f);
    float num = start[lblS[0]] + emS[lblS[0]] + part + endt[lblS[li]];
    atomicAdd(d_loss, -(num - denom) * (1.f / 32.f));
  }
}

// ---------------------------------------------------------- crf_viterbi -----
__global__ void crf_viterbi(const float* __restrict__ em, const int* __restrict__ mask,
                            const float* __restrict__ start, const float* __restrict__ endt,
                            const float* __restrict__ trans, float* __restrict__ preds) {
  __shared__ float emS[NT * NL];
  __shared__ int maskS[NT];
  __shared__ short bpS[(NT - 1) * NL];
  __shared__ short tagS[NT];
  const int b = blockIdx.x;
  const int tid = threadIdx.x;
  for (int i = tid; i < NT * NL; i += 64) emS[i] = em[(size_t)b * NT * NL + i];
  for (int i = tid; i < NT; i += 64) maskS[i] = mask[b * NT + i];
  __syncthreads();

  const int j = tid >> 2, q = tid & 3;
  const bool leader = (q == 0) && (j < NL);
  float tr0 = 0.f, tr1 = 0.f, tr2 = -1e30f;
  float score = 0.f;
  if (tid < 36) {
    tr0 = trans[q * NL + j];
    tr1 = trans[(q + 4) * NL + j];
    if (q == 0) tr2 = trans[8 * NL + j];
    if (leader) score = start[j] + emS[j];
  }
  for (int t = 1; t < NT; ++t) {
    float s0 = __shfl(score, q * 4, 64);
    float s1 = __shfl(score, (q + 4) * 4, 64);
    float s2 = __shfl(score, 32, 64);
    float v0 = s0 + tr0, v1 = s1 + tr1;
    float v2 = (q == 0) ? (s2 + tr2) : -1e30f;
    float bv = v0;
    int bi = q;
    if (v1 > bv) { bv = v1; bi = q + 4; }
    if (q == 0 && v2 > bv) { bv = v2; bi = 8; }
#pragma unroll
    for (int off = 1; off <= 2; off <<= 1) {
      float ov = __shfl_xor(bv, off, 4);
      int oi = __shfl_xor(bi, off, 4);
      if (ov > bv || (ov == bv && oi < bi)) { bv = ov; bi = oi; }
    }
    if (leader) {
      int keep = maskS[t];
      float nxt = bv + emS[t * NL + j];
      bpS[(t - 1) * NL + j] = keep ? (short)bi : (short)j;
      score = keep ? nxt : score;
    }
  }
  float fv[NL];
#pragma unroll
  for (int jj = 0; jj < NL; ++jj) fv[jj] = __shfl(score, jj * 4, 64) + endt[jj];
  if (tid == 0) {
    int last = 0;
    float bvv = fv[0];
#pragma unroll
    for (int jj = 1; jj < NL; ++jj)
      if (fv[jj] > bvv) { bvv = fv[jj]; last = jj; }
    tagS[NT - 1] = (short)last;
    for (int t = NT - 1; t >= 1; --t) tagS[t - 1] = bpS[(t - 1) * NL + tagS[t]];
  }
  __syncthreads();
  for (int i = tid; i < NT; i += 64) preds[(size_t)b * NT + i] = (float)tagS[i];
}

// ---------------------------------------------------------------------------
extern "C" void kernel_launch(void* const* d_in, const int* in_sizes, int n_in,
                              void* d_out, int out_size, void* d_ws, size_t ws_size,
                              hipStream_t stream) {
  const float* seq_out = (const float*)d_in[0];
  const int* attn = (const int*)d_in[1];
  const int* labels = (const int*)d_in[2];
  const float* w_ih_f = (const float*)d_in[3];
  const float* w_hh_f = (const float*)d_in[4];
  const float* b_f = (const float*)d_in[5];
  const float* w_ih_b = (const float*)d_in[6];
  const float* w_hh_b = (const float*)d_in[7];
  const float* b_b = (const float*)d_in[8];
  const float* w_tag = (const float*)d_in[9];
  const float* b_tag = (const float*)d_in[10];
  const float* start_t = (const float*)d_in[11];
  const float* end_t = (const float*)d_in[12];
  const float* trans = (const float*)d_in[13];
  (void)in_sizes; (void)n_in; (void)out_size; (void)ws_size;

  float* ws = (float*)d_ws;
  float* w_ihT = ws + OFF_WIHT;
  float* w_hhT = ws + OFF_WHHT;
  float* xpart = ws + OFF_XPART;
  float* hcat = ws + OFF_HCAT;
  float* hG = ws + OFF_HG;
  int* ctr = (int*)(ws + OFF_CTR);

  float* em = (float*)d_out;
  float* d_loss = em + NB * NT * NL;
  float* preds = d_loss + 1;

  prep<<<8192, 256, 0, stream>>>(w_ih_f, w_ih_b, w_hh_f, w_hh_b, w_ihT, w_hhT, d_loss, ctr);
  gemm_x<<<dim3(16, 128), 256, 0, stream>>>(seq_out, w_ihT, b_f, b_b, xpart);
  lstm_scan<<<64, 256, 0, stream>>>(w_hhT, xpart, hcat, hG, ctr);
  emissions<<<4096, 256, 0, stream>>>(hcat, w_tag, b_tag, em);
  crf_fwd<<<32, 64, 0, stream>>>(em, attn, labels, start_t, end_t, trans, d_loss);
  crf_viterbi<<<32, 64, 0, stream>>>(em, attn, start_t, end_t, trans, preds);
}

// Round 5
// 6633.624 us; speedup vs baseline: 1.7600x; 1.7600x over previous
//
#include <hip/hip_runtime.h>
#include <cmath>

// ---------------------------------------------------------------------------
// BertBiLSTMCRF round 5: LDS-resident weights + FENCELESS h-exchange.
// Round-4 lesson: threadfence (L1/L2 invalidate) per step = 21us/step, FETCH
// 400MB. Fix: h goes through agent-scope RELAXED atomic stores/loads that
// bypass caches to the die-level coherence point (L3 shared by all XCDs);
// no cache invalidation needed. Producer order: bypass-stores -> syncthreads
// (compiler drains vmcnt(0) at barrier) -> release flag add. Consumer: relaxed
// poll (control dep) -> barrier -> bypass loads. Parity double-buffer + per-
// step counters (proven race-free in round 4). Timeout guard vs hangs.
// ---------------------------------------------------------------------------

#define NB 32
#define NT 512
#define ND 768
#define NH 256
#define NG 1024   // 4*NH
#define NC 2048   // 2*NG
#define NL 9
#define NHC 512   // 2*NH
#define PPD 32    // blocks (slices) per direction
#define HPAD 260  // padded row stride for hS
#define GPAD 40   // padded row stride for gS (36 -> 40 kills 8-way conflict)
#define NBUF (2 * NB * NH)   // one parity buffer: [2 dirs][32 m][32 b][8 u]

static const size_t OFF_WIHT  = 0;                       // 1572864 floats
static const size_t OFF_WHHT  = 1572864;                 // 524288
static const size_t OFF_XPART = 2097152;                 // 33554432
static const size_t OFF_HCAT  = 35651584;                // 8388608
static const size_t OFF_HG    = 44040192;                // 2*16384 = 32768
static const size_t OFF_CTR   = 44072960;                // 1024 ints
// total ~44,073,984 floats = 176.3 MB

// ---------------------------------------------------------------- prep ------
__global__ void prep(const float* __restrict__ wihf, const float* __restrict__ wihb,
                     const float* __restrict__ whhf, const float* __restrict__ whhb,
                     float* __restrict__ w_ihT, float* __restrict__ w_hhT,
                     float* __restrict__ d_loss, int* __restrict__ ctr) {
  int idx = blockIdx.x * 256 + threadIdx.x;
  if (idx == 0) d_loss[0] = 0.f;
  if (idx < 1024) ctr[idx] = 0;          // 2*512 step counters
  if (idx < 1572864) {
    int k = idx >> 11;
    int c = idx & 2047;
    int d = c >> 10;
    int j = c & 1023;
    w_ihT[idx] = d ? wihb[j * ND + k] : wihf[j * ND + k];
  } else {
    int i2 = idx - 1572864;
    int d = i2 >> 18;
    int r = i2 & 262143;
    int k = r >> 10;
    int j = r & 1023;
    w_hhT[i2] = d ? whhb[j * NH + k] : whhf[j * NH + k];
  }
}

// -------------------------------------------------------------- gemm_x ------
__global__ __launch_bounds__(256, 2)
void gemm_x(const float* __restrict__ x, const float* __restrict__ wT,
            const float* __restrict__ bf, const float* __restrict__ bb,
            float* __restrict__ xpart) {
  __shared__ float As[8][128];
  __shared__ float Bs[8][128];
  const int tid = threadIdx.x;
  const int tx = tid & 15, ty = tid >> 4;
  const int r0 = blockIdx.y * 128, c0 = blockIdx.x * 128;

  float acc[8][8] = {};

  const int arow = tid >> 1;
  const int akq  = (tid & 1) * 4;
  const int rA = r0 + arow;
  const float* aptr = x + ((size_t)((rA & 31) * NT + (rA >> 5)) * ND) + akq;
  const int bk = tid >> 5;
  const int bc = (tid & 31) * 4;
  const float* bptr = wT + (size_t)bk * NC + c0 + bc;

  for (int k0 = 0; k0 < ND; k0 += 8) {
    float4 av = *(const float4*)(aptr + k0);
    float4 bv = *(const float4*)(bptr + (size_t)k0 * NC);
    __syncthreads();
    As[akq + 0][arow] = av.x;
    As[akq + 1][arow] = av.y;
    As[akq + 2][arow] = av.z;
    As[akq + 3][arow] = av.w;
    *(float4*)&Bs[bk][bc] = bv;
    __syncthreads();
#pragma unroll
    for (int k = 0; k < 8; ++k) {
      float4 a0 = *(const float4*)&As[k][ty * 8];
      float4 a1 = *(const float4*)&As[k][ty * 8 + 4];
      float4 b0 = *(const float4*)&Bs[k][tx * 8];
      float4 b1 = *(const float4*)&Bs[k][tx * 8 + 4];
      float am[8] = {a0.x, a0.y, a0.z, a0.w, a1.x, a1.y, a1.z, a1.w};
      float bm[8] = {b0.x, b0.y, b0.z, b0.w, b1.x, b1.y, b1.z, b1.w};
#pragma unroll
      for (int i = 0; i < 8; ++i)
#pragma unroll
        for (int j = 0; j < 8; ++j) acc[i][j] += am[i] * bm[j];
    }
  }

  const int cbase = c0 + tx * 8;
  float bias[8];
#pragma unroll
  for (int j = 0; j < 8; ++j) {
    int c = cbase + j;
    bias[j] = (c < NG) ? bf[c] : bb[c - NG];
  }
#pragma unroll
  for (int i = 0; i < 8; ++i) {
    int r = r0 + ty * 8 + i;
    float4 v0 = {acc[i][0] + bias[0], acc[i][1] + bias[1],
                 acc[i][2] + bias[2], acc[i][3] + bias[3]};
    float4 v1 = {acc[i][4] + bias[4], acc[i][5] + bias[5],
                 acc[i][6] + bias[6], acc[i][7] + bias[7]};
    *(float4*)(xpart + (size_t)r * NC + cbase) = v0;
    *(float4*)(xpart + (size_t)r * NC + cbase + 4) = v1;
  }
}

// ------------------------------------------------------------ lstm_scan -----
__global__ __launch_bounds__(256, 1)
void lstm_scan(const float* __restrict__ whhT, const float* __restrict__ xpart,
               float* __restrict__ hcat, float* __restrict__ hG,
               int* __restrict__ ctr) {
  __shared__ float wS[256 * 32];      // [k][l]
  __shared__ float hS[32 * HPAD];     // [b][k], padded
  __shared__ float gS[32 * GPAD];     // [b][l], padded
  const int tid = threadIdx.x;
  const int d = blockIdx.x >> 5;
  const int m = blockIdx.x & 31;

  // one-time weight slice load: wS[k][l], l=g*8+u -> col g*256+m*8+u
  const float* wsrc = whhT + (size_t)d * NH * NG;
  for (int it = 0; it < 32; ++it) {
    int i = it * 256 + tid;
    int k = i >> 5, l = i & 31;
    int g = l >> 3, u2 = l & 7;
    wS[k * 32 + l] = wsrc[(size_t)k * NG + g * 256 + m * 8 + u2];
  }
  for (int i = tid; i < 32 * HPAD; i += 256) hS[i] = 0.f;
  __syncthreads();

  const int b = tid >> 3;
  const int cg = tid & 7;
  const int u = tid & 7;
  const int l0 = cg * 4;
  const int g4 = l0 >> 3, u04 = l0 & 7;
  const int col4 = g4 * 256 + m * 8 + u04;   // 4 consecutive gate cols
  int* ctrd = ctr + d * NT;

  float c = 0.f;
  for (int s = 0; s < NT; ++s) {
    const int t = d ? (NT - 1 - s) : s;
    float4 xv = *(const float4*)(xpart + ((size_t)(t * NB + b) * NC) + d * NG + col4);
    float4 acc = {0.f, 0.f, 0.f, 0.f};
    const float* hrow = &hS[b * HPAD];
    for (int k0 = 0; k0 < NH; k0 += 4) {
      float4 hv = *(const float4*)(hrow + k0);
      {
        float4 wv = *(const float4*)(&wS[(k0 + 0) * 32 + l0]);
        acc.x += hv.x * wv.x; acc.y += hv.x * wv.y; acc.z += hv.x * wv.z; acc.w += hv.x * wv.w;
      }
      {
        float4 wv = *(const float4*)(&wS[(k0 + 1) * 32 + l0]);
        acc.x += hv.y * wv.x; acc.y += hv.y * wv.y; acc.z += hv.y * wv.z; acc.w += hv.y * wv.w;
      }
      {
        float4 wv = *(const float4*)(&wS[(k0 + 2) * 32 + l0]);
        acc.x += hv.z * wv.x; acc.y += hv.z * wv.y; acc.z += hv.z * wv.z; acc.w += hv.z * wv.w;
      }
      {
        float4 wv = *(const float4*)(&wS[(k0 + 3) * 32 + l0]);
        acc.x += hv.w * wv.x; acc.y += hv.w * wv.y; acc.z += hv.w * wv.z; acc.w += hv.w * wv.w;
      }
    }
    acc.x += xv.x; acc.y += xv.y; acc.z += xv.z; acc.w += xv.w;
    *(float4*)(&gS[b * GPAD + l0]) = acc;
    __syncthreads();

    // c/h update for (b, unit m*8+u)
    float gi = gS[b * GPAD + u];
    float gf = gS[b * GPAD + 8 + u];
    float gg = gS[b * GPAD + 16 + u];
    float go = gS[b * GPAD + 24 + u];
    float ii = 1.f / (1.f + expf(-gi));
    float ff = 1.f / (1.f + expf(-gf));
    float tg = tanhf(gg);
    float oo = 1.f / (1.f + expf(-go));
    c = ff * c + ii * tg;
    float h = oo * tanhf(c);
    hcat[((size_t)(b * NT + t)) * NHC + d * NH + m * 8 + u] = h;

    if (s < NT - 1) {
      // publish own slice: hG[par][d][m][b*8+u], contiguous 1KB per block,
      // cache-bypass store to coherence point (no invalidates needed later)
      float* dst = hG + ((s & 1) ? NBUF : 0) + d * 8192 + m * 256;
      __hip_atomic_store(&dst[tid], h, __ATOMIC_RELAXED, __HIP_MEMORY_SCOPE_AGENT);
      __syncthreads();   // compiler drains vmcnt(0) per wave before s_barrier
      if (tid == 0)
        __hip_atomic_fetch_add(&ctrd[s], 1, __ATOMIC_RELEASE,
                               __HIP_MEMORY_SCOPE_AGENT);
      if ((tid & 63) == 0) {
        long long t0 = wall_clock64();
        while (__hip_atomic_load(&ctrd[s], __ATOMIC_RELAXED,
                                 __HIP_MEMORY_SCOPE_AGENT) < PPD) {
          if (wall_clock64() - t0 > 5000000LL) break;  // ~50ms hang guard
        }
      }
      __syncthreads();
      // read back full h for own direction via bypass loads (8B each)
      const unsigned long long* src = (const unsigned long long*)
          (hG + ((s & 1) ? NBUF : 0) + d * 8192);
#pragma unroll
      for (int i = 0; i < 16; ++i) {
        int f = i * 256 + tid;            // float2 index 0..4095
        unsigned long long v = __hip_atomic_load(&src[f], __ATOMIC_RELAXED,
                                                 __HIP_MEMORY_SCOPE_AGENT);
        union { unsigned long long uu; float ff2[2]; } cv;
        cv.uu = v;
        int mq = f >> 7;
        int r = f & 127;
        int bb = r >> 2;
        int u2 = (r & 3) * 2;
        hS[bb * HPAD + mq * 8 + u2] = cv.ff2[0];
        hS[bb * HPAD + mq * 8 + u2 + 1] = cv.ff2[1];
      }
      __syncthreads();
    }
  }
}

// ------------------------------------------------------------ emissions -----
__global__ void emissions(const float* __restrict__ hcat, const float* __restrict__ wtag,
                          const float* __restrict__ btag, float* __restrict__ em) {
  __shared__ float wS[NL * NHC];
  const int tid = threadIdx.x;
  for (int i = tid; i < NL * NHC; i += 256) wS[i] = wtag[i];
  __syncthreads();
  const int w = tid >> 6, l = tid & 63;
  const int r = blockIdx.x * 4 + w;
  const float* hp = hcat + (size_t)r * NHC;
  float acc[NL] = {};
#pragma unroll
  for (int rep = 0; rep < 8; ++rep) {
    float hv = hp[l + rep * 64];
#pragma unroll
    for (int j = 0; j < NL; ++j) acc[j] += hv * wS[j * NHC + l + rep * 64];
  }
#pragma unroll
  for (int j = 0; j < NL; ++j) {
#pragma unroll
    for (int off = 32; off; off >>= 1) acc[j] += __shfl_xor(acc[j], off, 64);
  }
  if (l == 0) {
#pragma unroll
    for (int j = 0; j < NL; ++j) em[(size_t)r * NL + j] = acc[j] + btag[j];
  }
}

// -------------------------------------------------------------- crf_fwd -----
__global__ void crf_fwd(const float* __restrict__ em, const int* __restrict__ mask,
                        const int* __restrict__ labels, const float* __restrict__ start,
                        const float* __restrict__ endt, const float* __restrict__ trans,
                        float* __restrict__ d_loss) {
  __shared__ float emS[NT * NL];
  __shared__ float maskS[NT];
  __shared__ int lblS[NT];
  const int b = blockIdx.x;
  const int tid = threadIdx.x;
  for (int i = tid; i < NT * NL; i += 64) emS[i] = em[(size_t)b * NT * NL + i];
  for (int i = tid; i < NT; i += 64) {
    maskS[i] = (float)mask[b * NT + i];
    int lb = labels[b * NT + i];
    lblS[i] = (lb == -100) ? 0 : lb;
  }
  __syncthreads();

  float part = 0.f, msum = 0.f;
  for (int t = tid; t < NT; t += 64) {
    msum += maskS[t];
    if (t >= 1)
      part += (trans[lblS[t - 1] * NL + lblS[t]] + emS[t * NL + lblS[t]]) * maskS[t];
  }
#pragma unroll
  for (int off = 32; off; off >>= 1) {
    part += __shfl_xor(part, off, 64);
    msum += __shfl_xor(msum, off, 64);
  }

  const int j = tid >> 2, q = tid & 3;
  const bool leader = (q == 0) && (j < NL);
  float tr0 = 0.f, tr1 = 0.f, tr2 = -1e30f;
  float score = 0.f;
  if (tid < 36) {
    tr0 = trans[q * NL + j];
    tr1 = trans[(q + 4) * NL + j];
    if (q == 0) tr2 = trans[8 * NL + j];
    if (leader) score = start[j] + emS[j];
  }
  for (int t = 1; t < NT; ++t) {
    float s0 = __shfl(score, q * 4, 64);
    float s1 = __shfl(score, (q + 4) * 4, 64);
    float s2 = __shfl(score, 32, 64);
    float v0 = s0 + tr0, v1 = s1 + tr1;
    float v2 = (q == 0) ? (s2 + tr2) : -1e30f;
    float m = fmaxf(fmaxf(v0, v1), v2);
    m = fmaxf(m, __shfl_xor(m, 1, 4));
    m = fmaxf(m, __shfl_xor(m, 2, 4));
    float e = expf(v0 - m) + expf(v1 - m) + ((q == 0) ? expf(v2 - m) : 0.f);
    e += __shfl_xor(e, 1, 4);
    e += __shfl_xor(e, 2, 4);
    if (leader) {
      float nxt = m + logf(e) + emS[t * NL + j];
      score = (maskS[t] > 0.f) ? nxt : score;
    }
  }
  float vs[NL];
  float mx = -1e30f;
#pragma unroll
  for (int jj = 0; jj < NL; ++jj) {
    float sj = __shfl(score, jj * 4, 64) + endt[jj];
    vs[jj] = sj;
    mx = fmaxf(mx, sj);
  }
  float se = 0.f;
#pragma unroll
  for (int jj = 0; jj < NL; ++jj) se += expf(vs[jj] - mx);
  float denom = mx + logf(se);
  if (tid == 0) {
    int li = (int)(msum - 0.5f);
    float num = start[lblS[0]] + emS[lblS[0]] + part + endt[lblS[li]];
    atomicAdd(d_loss, -(num - denom) * (1.f / 32.f));
  }
}

// ---------------------------------------------------------- crf_viterbi -----
__global__ void crf_viterbi(const float* __restrict__ em, const int* __restrict__ mask,
                            const float* __restrict__ start, const float* __restrict__ endt,
                            const float* __restrict__ trans, float* __restrict__ preds) {
  __shared__ float emS[NT * NL];
  __shared__ int maskS[NT];
  __shared__ short bpS[(NT - 1) * NL];
  __shared__ short tagS[NT];
  const int b = blockIdx.x;
  const int tid = threadIdx.x;
  for (int i = tid; i < NT * NL; i += 64) emS[i] = em[(size_t)b * NT * NL + i];
  for (int i = tid; i < NT; i += 64) maskS[i] = mask[b * NT + i];
  __syncthreads();

  const int j = tid >> 2, q = tid & 3;
  const bool leader = (q == 0) && (j < NL);
  float tr0 = 0.f, tr1 = 0.f, tr2 = -1e30f;
  float score = 0.f;
  if (tid < 36) {
    tr0 = trans[q * NL + j];
    tr1 = trans[(q + 4) * NL + j];
    if (q == 0) tr2 = trans[8 * NL + j];
    if (leader) score = start[j] + emS[j];
  }
  for (int t = 1; t < NT; ++t) {
    float s0 = __shfl(score, q * 4, 64);
    float s1 = __shfl(score, (q + 4) * 4, 64);
    float s2 = __shfl(score, 32, 64);
    float v0 = s0 + tr0, v1 = s1 + tr1;
    float v2 = (q == 0) ? (s2 + tr2) : -1e30f;
    float bv = v0;
    int bi = q;
    if (v1 > bv) { bv = v1; bi = q + 4; }
    if (q == 0 && v2 > bv) { bv = v2; bi = 8; }
#pragma unroll
    for (int off = 1; off <= 2; off <<= 1) {
      float ov = __shfl_xor(bv, off, 4);
      int oi = __shfl_xor(bi, off, 4);
      if (ov > bv || (ov == bv && oi < bi)) { bv = ov; bi = oi; }
    }
    if (leader) {
      int keep = maskS[t];
      float nxt = bv + emS[t * NL + j];
      bpS[(t - 1) * NL + j] = keep ? (short)bi : (short)j;
      score = keep ? nxt : score;
    }
  }
  float fv[NL];
#pragma unroll
  for (int jj = 0; jj < NL; ++jj) fv[jj] = __shfl(score, jj * 4, 64) + endt[jj];
  if (tid == 0) {
    int last = 0;
    float bvv = fv[0];
#pragma unroll
    for (int jj = 1; jj < NL; ++jj)
      if (fv[jj] > bvv) { bvv = fv[jj]; last = jj; }
    tagS[NT - 1] = (short)last;
    for (int t = NT - 1; t >= 1; --t) tagS[t - 1] = bpS[(t - 1) * NL + tagS[t]];
  }
  __syncthreads();
  for (int i = tid; i < NT; i += 64) preds[(size_t)b * NT + i] = (float)tagS[i];
}

// ---------------------------------------------------------------------------
extern "C" void kernel_launch(void* const* d_in, const int* in_sizes, int n_in,
                              void* d_out, int out_size, void* d_ws, size_t ws_size,
                              hipStream_t stream) {
  const float* seq_out = (const float*)d_in[0];
  const int* attn = (const int*)d_in[1];
  const int* labels = (const int*)d_in[2];
  const float* w_ih_f = (const float*)d_in[3];
  const float* w_hh_f = (const float*)d_in[4];
  const float* b_f = (const float*)d_in[5];
  const float* w_ih_b = (const float*)d_in[6];
  const float* w_hh_b = (const float*)d_in[7];
  const float* b_b = (const float*)d_in[8];
  const float* w_tag = (const float*)d_in[9];
  const float* b_tag = (const float*)d_in[10];
  const float* start_t = (const float*)d_in[11];
  const float* end_t = (const float*)d_in[12];
  const float* trans = (const float*)d_in[13];
  (void)in_sizes; (void)n_in; (void)out_size; (void)ws_size;

  float* ws = (float*)d_ws;
  float* w_ihT = ws + OFF_WIHT;
  float* w_hhT = ws + OFF_WHHT;
  float* xpart = ws + OFF_XPART;
  float* hcat = ws + OFF_HCAT;
  float* hG = ws + OFF_HG;
  int* ctr = (int*)(ws + OFF_CTR);

  float* em = (float*)d_out;
  float* d_loss = em + NB * NT * NL;
  float* preds = d_loss + 1;

  prep<<<8192, 256, 0, stream>>>(w_ih_f, w_ih_b, w_hh_f, w_hh_b, w_ihT, w_hhT, d_loss, ctr);
  gemm_x<<<dim3(16, 128), 256, 0, stream>>>(seq_out, w_ihT, b_f, b_b, xpart);
  lstm_scan<<<64, 256, 0, stream>>>(w_hhT, xpart, hcat, hG, ctr);
  emissions<<<4096, 256, 0, stream>>>(hcat, w_tag, b_tag, em);
  crf_fwd<<<32, 64, 0, stream>>>(em, attn, labels, start_t, end_t, trans, d_loss);
  crf_viterbi<<<32, 64, 0, stream>>>(em, attn, start_t, end_t, trans, preds);
}

// Round 6
// 6418.385 us; speedup vs baseline: 1.8190x; 1.0335x over previous
//
#include <hip/hip_runtime.h>
#include <cmath>

// ---------------------------------------------------------------------------
// BertBiLSTMCRF round 6: per-block FLAG ARRAY instead of counter atomicAdd.
// Round-5 lesson: 32 serialized RMWs/step on one L3 line ~= 6us/step. Fix:
// each block relaxed/release-STOREs s+1 to its own flag slot; consumers poll
// all 32 flags with one coalesced 128B wave load + ballot (1 L3 trip/iter).
// Parity double-buffer still race-free: flag[X]>=s+2 => X consumed buf[s&1];
// writer touches buf[s&1] again only after waiting flags>=s+2.
// h exchange stays agent-scope bypass atomics (no cache invalidates).
// ---------------------------------------------------------------------------

#define NB 32
#define NT 512
#define ND 768
#define NH 256
#define NG 1024   // 4*NH
#define NC 2048   // 2*NG
#define NL 9
#define NHC 512   // 2*NH
#define PPD 32    // blocks (slices) per direction
#define HPAD 260  // padded row stride for hS
#define GPAD 40   // padded row stride for gS
#define NBUF (2 * NB * NH)   // one parity buffer: [2 dirs][32 m][32 b][8 u]

static const size_t OFF_WIHT  = 0;                       // 1572864 floats
static const size_t OFF_WHHT  = 1572864;                 // 524288
static const size_t OFF_XPART = 2097152;                 // 33554432
static const size_t OFF_HCAT  = 35651584;                // 8388608
static const size_t OFF_HG    = 44040192;                // 2*16384 = 32768
static const size_t OFF_CTR   = 44072960;                // 1024 ints (flags)
// total ~44,073,984 floats = 176.3 MB

// ---------------------------------------------------------------- prep ------
__global__ void prep(const float* __restrict__ wihf, const float* __restrict__ wihb,
                     const float* __restrict__ whhf, const float* __restrict__ whhb,
                     float* __restrict__ w_ihT, float* __restrict__ w_hhT,
                     float* __restrict__ d_loss, int* __restrict__ flags) {
  int idx = blockIdx.x * 256 + threadIdx.x;
  if (idx == 0) d_loss[0] = 0.f;
  if (idx < 1024) flags[idx] = 0;        // [d][m] step flags (only 64 used)
  if (idx < 1572864) {
    int k = idx >> 11;
    int c = idx & 2047;
    int d = c >> 10;
    int j = c & 1023;
    w_ihT[idx] = d ? wihb[j * ND + k] : wihf[j * ND + k];
  } else {
    int i2 = idx - 1572864;
    int d = i2 >> 18;
    int r = i2 & 262143;
    int k = r >> 10;
    int j = r & 1023;
    w_hhT[i2] = d ? whhb[j * NH + k] : whhf[j * NH + k];
  }
}

// -------------------------------------------------------------- gemm_x ------
__global__ __launch_bounds__(256, 2)
void gemm_x(const float* __restrict__ x, const float* __restrict__ wT,
            const float* __restrict__ bf, const float* __restrict__ bb,
            float* __restrict__ xpart) {
  __shared__ float As[8][128];
  __shared__ float Bs[8][128];
  const int tid = threadIdx.x;
  const int tx = tid & 15, ty = tid >> 4;
  const int r0 = blockIdx.y * 128, c0 = blockIdx.x * 128;

  float acc[8][8] = {};

  const int arow = tid >> 1;
  const int akq  = (tid & 1) * 4;
  const int rA = r0 + arow;
  const float* aptr = x + ((size_t)((rA & 31) * NT + (rA >> 5)) * ND) + akq;
  const int bk = tid >> 5;
  const int bc = (tid & 31) * 4;
  const float* bptr = wT + (size_t)bk * NC + c0 + bc;

  for (int k0 = 0; k0 < ND; k0 += 8) {
    float4 av = *(const float4*)(aptr + k0);
    float4 bv = *(const float4*)(bptr + (size_t)k0 * NC);
    __syncthreads();
    As[akq + 0][arow] = av.x;
    As[akq + 1][arow] = av.y;
    As[akq + 2][arow] = av.z;
    As[akq + 3][arow] = av.w;
    *(float4*)&Bs[bk][bc] = bv;
    __syncthreads();
#pragma unroll
    for (int k = 0; k < 8; ++k) {
      float4 a0 = *(const float4*)&As[k][ty * 8];
      float4 a1 = *(const float4*)&As[k][ty * 8 + 4];
      float4 b0 = *(const float4*)&Bs[k][tx * 8];
      float4 b1 = *(const float4*)&Bs[k][tx * 8 + 4];
      float am[8] = {a0.x, a0.y, a0.z, a0.w, a1.x, a1.y, a1.z, a1.w};
      float bm[8] = {b0.x, b0.y, b0.z, b0.w, b1.x, b1.y, b1.z, b1.w};
#pragma unroll
      for (int i = 0; i < 8; ++i)
#pragma unroll
        for (int j = 0; j < 8; ++j) acc[i][j] += am[i] * bm[j];
    }
  }

  const int cbase = c0 + tx * 8;
  float bias[8];
#pragma unroll
  for (int j = 0; j < 8; ++j) {
    int c = cbase + j;
    bias[j] = (c < NG) ? bf[c] : bb[c - NG];
  }
#pragma unroll
  for (int i = 0; i < 8; ++i) {
    int r = r0 + ty * 8 + i;
    float4 v0 = {acc[i][0] + bias[0], acc[i][1] + bias[1],
                 acc[i][2] + bias[2], acc[i][3] + bias[3]};
    float4 v1 = {acc[i][4] + bias[4], acc[i][5] + bias[5],
                 acc[i][6] + bias[6], acc[i][7] + bias[7]};
    *(float4*)(xpart + (size_t)r * NC + cbase) = v0;
    *(float4*)(xpart + (size_t)r * NC + cbase + 4) = v1;
  }
}

// ------------------------------------------------------------ lstm_scan -----
__global__ __launch_bounds__(256, 1)
void lstm_scan(const float* __restrict__ whhT, const float* __restrict__ xpart,
               float* __restrict__ hcat, float* __restrict__ hG,
               int* __restrict__ flags) {
  __shared__ float wS[256 * 32];      // [k][l]
  __shared__ float hS[32 * HPAD];     // [b][k], padded
  __shared__ float gS[32 * GPAD];     // [b][l], padded
  const int tid = threadIdx.x;
  const int d = blockIdx.x >> 5;
  const int m = blockIdx.x & 31;

  // one-time weight slice load: wS[k][l], l=g*8+u -> col g*256+m*8+u
  const float* wsrc = whhT + (size_t)d * NH * NG;
  for (int it = 0; it < 32; ++it) {
    int i = it * 256 + tid;
    int k = i >> 5, l = i & 31;
    int g = l >> 3, u2 = l & 7;
    wS[k * 32 + l] = wsrc[(size_t)k * NG + g * 256 + m * 8 + u2];
  }
  for (int i = tid; i < 32 * HPAD; i += 256) hS[i] = 0.f;
  __syncthreads();

  const int b = tid >> 3;
  const int cg = tid & 7;
  const int u = tid & 7;
  const int l0 = cg * 4;
  const int g4 = l0 >> 3, u04 = l0 & 7;
  const int col4 = g4 * 256 + m * 8 + u04;   // 4 consecutive gate cols
  int* flagd = flags + d * PPD;
  const int lane = tid & 63;

  float c = 0.f;
  for (int s = 0; s < NT; ++s) {
    const int t = d ? (NT - 1 - s) : s;
    float4 xv = *(const float4*)(xpart + ((size_t)(t * NB + b) * NC) + d * NG + col4);
    float4 acc = {0.f, 0.f, 0.f, 0.f};
    const float* hrow = &hS[b * HPAD];
    for (int k0 = 0; k0 < NH; k0 += 4) {
      float4 hv = *(const float4*)(hrow + k0);
      {
        float4 wv = *(const float4*)(&wS[(k0 + 0) * 32 + l0]);
        acc.x += hv.x * wv.x; acc.y += hv.x * wv.y; acc.z += hv.x * wv.z; acc.w += hv.x * wv.w;
      }
      {
        float4 wv = *(const float4*)(&wS[(k0 + 1) * 32 + l0]);
        acc.x += hv.y * wv.x; acc.y += hv.y * wv.y; acc.z += hv.y * wv.z; acc.w += hv.y * wv.w;
      }
      {
        float4 wv = *(const float4*)(&wS[(k0 + 2) * 32 + l0]);
        acc.x += hv.z * wv.x; acc.y += hv.z * wv.y; acc.z += hv.z * wv.z; acc.w += hv.z * wv.w;
      }
      {
        float4 wv = *(const float4*)(&wS[(k0 + 3) * 32 + l0]);
        acc.x += hv.w * wv.x; acc.y += hv.w * wv.y; acc.z += hv.w * wv.z; acc.w += hv.w * wv.w;
      }
    }
    acc.x += xv.x; acc.y += xv.y; acc.z += xv.z; acc.w += xv.w;
    *(float4*)(&gS[b * GPAD + l0]) = acc;
    __syncthreads();

    // c/h update for (b, unit m*8+u)
    float gi = gS[b * GPAD + u];
    float gf = gS[b * GPAD + 8 + u];
    float gg = gS[b * GPAD + 16 + u];
    float go = gS[b * GPAD + 24 + u];
    float ii = 1.f / (1.f + expf(-gi));
    float ff = 1.f / (1.f + expf(-gf));
    float tg = tanhf(gg);
    float oo = 1.f / (1.f + expf(-go));
    c = ff * c + ii * tg;
    float h = oo * tanhf(c);
    hcat[((size_t)(b * NT + t)) * NHC + d * NH + m * 8 + u] = h;

    if (s < NT - 1) {
      // publish own slice (cache-bypass, contiguous 1KB per block)
      float* dst = hG + ((s & 1) ? NBUF : 0) + d * 8192 + m * 256;
      __hip_atomic_store(&dst[tid], h, __ATOMIC_RELAXED, __HIP_MEMORY_SCOPE_AGENT);
      __syncthreads();   // per-wave vmcnt(0) drain before s_barrier
      if (tid == 0)
        __hip_atomic_store(&flagd[m], s + 1, __ATOMIC_RELEASE,
                           __HIP_MEMORY_SCOPE_AGENT);
      // all waves poll the 32-flag array: one coalesced 128B load + ballot
      {
        long long t0 = wall_clock64();
        for (;;) {
          int v = (lane < PPD)
              ? __hip_atomic_load(&flagd[lane], __ATOMIC_RELAXED,
                                  __HIP_MEMORY_SCOPE_AGENT)
              : 0x7fffffff;
          if (__ballot(v > s) == ~0ULL) break;
          if (wall_clock64() - t0 > 5000000LL) break;  // ~50ms hang guard
        }
      }
      __syncthreads();
      // read back full h for own direction via bypass loads (8B each)
      const unsigned long long* src = (const unsigned long long*)
          (hG + ((s & 1) ? NBUF : 0) + d * 8192);
#pragma unroll
      for (int i = 0; i < 16; ++i) {
        int f = i * 256 + tid;            // float2 index 0..4095
        unsigned long long v = __hip_atomic_load(&src[f], __ATOMIC_RELAXED,
                                                 __HIP_MEMORY_SCOPE_AGENT);
        union { unsigned long long uu; float ff2[2]; } cv;
        cv.uu = v;
        int mq = f >> 7;
        int r = f & 127;
        int bb = r >> 2;
        int u2 = (r & 3) * 2;
        hS[bb * HPAD + mq * 8 + u2] = cv.ff2[0];
        hS[bb * HPAD + mq * 8 + u2 + 1] = cv.ff2[1];
      }
      __syncthreads();
    }
  }
}

// ------------------------------------------------------------ emissions -----
__global__ void emissions(const float* __restrict__ hcat, const float* __restrict__ wtag,
                          const float* __restrict__ btag, float* __restrict__ em) {
  __shared__ float wS[NL * NHC];
  const int tid = threadIdx.x;
  for (int i = tid; i < NL * NHC; i += 256) wS[i] = wtag[i];
  __syncthreads();
  const int w = tid >> 6, l = tid & 63;
  const int r = blockIdx.x * 4 + w;
  const float* hp = hcat + (size_t)r * NHC;
  float acc[NL] = {};
#pragma unroll
  for (int rep = 0; rep < 8; ++rep) {
    float hv = hp[l + rep * 64];
#pragma unroll
    for (int j = 0; j < NL; ++j) acc[j] += hv * wS[j * NHC + l + rep * 64];
  }
#pragma unroll
  for (int j = 0; j < NL; ++j) {
#pragma unroll
    for (int off = 32; off; off >>= 1) acc[j] += __shfl_xor(acc[j], off, 64);
  }
  if (l == 0) {
#pragma unroll
    for (int j = 0; j < NL; ++j) em[(size_t)r * NL + j] = acc[j] + btag[j];
  }
}

// -------------------------------------------------------------- crf_fwd -----
__global__ void crf_fwd(const float* __restrict__ em, const int* __restrict__ mask,
                        const int* __restrict__ labels, const float* __restrict__ start,
                        const float* __restrict__ endt, const float* __restrict__ trans,
                        float* __restrict__ d_loss) {
  __shared__ float emS[NT * NL];
  __shared__ float maskS[NT];
  __shared__ int lblS[NT];
  const int b = blockIdx.x;
  const int tid = threadIdx.x;
  for (int i = tid; i < NT * NL; i += 64) emS[i] = em[(size_t)b * NT * NL + i];
  for (int i = tid; i < NT; i += 64) {
    maskS[i] = (float)mask[b * NT + i];
    int lb = labels[b * NT + i];
    lblS[i] = (lb == -100) ? 0 : lb;
  }
  __syncthreads();

  float part = 0.f, msum = 0.f;
  for (int t = tid; t < NT; t += 64) {
    msum += maskS[t];
    if (t >= 1)
      part += (trans[lblS[t - 1] * NL + lblS[t]] + emS[t * NL + lblS[t]]) * maskS[t];
  }
#pragma unroll
  for (int off = 32; off; off >>= 1) {
    part += __shfl_xor(part, off, 64);
    msum += __shfl_xor(msum, off, 64);
  }

  const int j = tid >> 2, q = tid & 3;
  const bool leader = (q == 0) && (j < NL);
  float tr0 = 0.f, tr1 = 0.f, tr2 = -1e30f;
  float score = 0.f;
  if (tid < 36) {
    tr0 = trans[q * NL + j];
    tr1 = trans[(q + 4) * NL + j];
    if (q == 0) tr2 = trans[8 * NL + j];
    if (leader) score = start[j] + emS[j];
  }
  for (int t = 1; t < NT; ++t) {
    float s0 = __shfl(score, q * 4, 64);
    float s1 = __shfl(score, (q + 4) * 4, 64);
    float s2 = __shfl(score, 32, 64);
    float v0 = s0 + tr0, v1 = s1 + tr1;
    float v2 = (q == 0) ? (s2 + tr2) : -1e30f;
    float m = fmaxf(fmaxf(v0, v1), v2);
    m = fmaxf(m, __shfl_xor(m, 1, 4));
    m = fmaxf(m, __shfl_xor(m, 2, 4));
    float e = expf(v0 - m) + expf(v1 - m) + ((q == 0) ? expf(v2 - m) : 0.f);
    e += __shfl_xor(e, 1, 4);
    e += __shfl_xor(e, 2, 4);
    if (leader) {
      float nxt = m + logf(e) + emS[t * NL + j];
      score = (maskS[t] > 0.f) ? nxt : score;
    }
  }
  float vs[NL];
  float mx = -1e30f;
#pragma unroll
  for (int jj = 0; jj < NL; ++jj) {
    float sj = __shfl(score, jj * 4, 64) + endt[jj];
    vs[jj] = sj;
    mx = fmaxf(mx, sj);
  }
  float se = 0.f;
#pragma unroll
  for (int jj = 0; jj < NL; ++jj) se += expf(vs[jj] - mx);
  float denom = mx + logf(se);
  if (tid == 0) {
    int li = (int)(msum - 0.5f);
    float num = start[lblS[0]] + emS[lblS[0]] + part + endt[lblS[li]];
    atomicAdd(d_loss, -(num - denom) * (1.f / 32.f));
  }
}

// ---------------------------------------------------------- crf_viterbi -----
__global__ void crf_viterbi(const float* __restrict__ em, const int* __restrict__ mask,
                            const float* __restrict__ start, const float* __restrict__ endt,
                            const float* __restrict__ trans, float* __restrict__ preds) {
  __shared__ float emS[NT * NL];
  __shared__ int maskS[NT];
  __shared__ short bpS[(NT - 1) * NL];
  __shared__ short tagS[NT];
  const int b = blockIdx.x;
  const int tid = threadIdx.x;
  for (int i = tid; i < NT * NL; i += 64) emS[i] = em[(size_t)b * NT * NL + i];
  for (int i = tid; i < NT; i += 64) maskS[i] = mask[b * NT + i];
  __syncthreads();

  const int j = tid >> 2, q = tid & 3;
  const bool leader = (q == 0) && (j < NL);
  float tr0 = 0.f, tr1 = 0.f, tr2 = -1e30f;
  float score = 0.f;
  if (tid < 36) {
    tr0 = trans[q * NL + j];
    tr1 = trans[(q + 4) * NL + j];
    if (q == 0) tr2 = trans[8 * NL + j];
    if (leader) score = start[j] + emS[j];
  }
  for (int t = 1; t < NT; ++t) {
    float s0 = __shfl(score, q * 4, 64);
    float s1 = __shfl(score, (q + 4) * 4, 64);
    float s2 = __shfl(score, 32, 64);
    float v0 = s0 + tr0, v1 = s1 + tr1;
    float v2 = (q == 0) ? (s2 + tr2) : -1e30f;
    float bv = v0;
    int bi = q;
    if (v1 > bv) { bv = v1; bi = q + 4; }
    if (q == 0 && v2 > bv) { bv = v2; bi = 8; }
#pragma unroll
    for (int off = 1; off <= 2; off <<= 1) {
      float ov = __shfl_xor(bv, off, 4);
      int oi = __shfl_xor(bi, off, 4);
      if (ov > bv || (ov == bv && oi < bi)) { bv = ov; bi = oi; }
    }
    if (leader) {
      int keep = maskS[t];
      float nxt = bv + emS[t * NL + j];
      bpS[(t - 1) * NL + j] = keep ? (short)bi : (short)j;
      score = keep ? nxt : score;
    }
  }
  float fv[NL];
#pragma unroll
  for (int jj = 0; jj < NL; ++jj) fv[jj] = __shfl(score, jj * 4, 64) + endt[jj];
  if (tid == 0) {
    int last = 0;
    float bvv = fv[0];
#pragma unroll
    for (int jj = 1; jj < NL; ++jj)
      if (fv[jj] > bvv) { bvv = fv[jj]; last = jj; }
    tagS[NT - 1] = (short)last;
    for (int t = NT - 1; t >= 1; --t) tagS[t - 1] = bpS[(t - 1) * NL + tagS[t]];
  }
  __syncthreads();
  for (int i = tid; i < NT; i += 64) preds[(size_t)b * NT + i] = (float)tagS[i];
}

// ---------------------------------------------------------------------------
extern "C" void kernel_launch(void* const* d_in, const int* in_sizes, int n_in,
                              void* d_out, int out_size, void* d_ws, size_t ws_size,
                              hipStream_t stream) {
  const float* seq_out = (const float*)d_in[0];
  const int* attn = (const int*)d_in[1];
  const int* labels = (const int*)d_in[2];
  const float* w_ih_f = (const float*)d_in[3];
  const float* w_hh_f = (const float*)d_in[4];
  const float* b_f = (const float*)d_in[5];
  const float* w_ih_b = (const float*)d_in[6];
  const float* w_hh_b = (const float*)d_in[7];
  const float* b_b = (const float*)d_in[8];
  const float* w_tag = (const float*)d_in[9];
  const float* b_tag = (const float*)d_in[10];
  const float* start_t = (const float*)d_in[11];
  const float* end_t = (const float*)d_in[12];
  const float* trans = (const float*)d_in[13];
  (void)in_sizes; (void)n_in; (void)out_size; (void)ws_size;

  float* ws = (float*)d_ws;
  float* w_ihT = ws + OFF_WIHT;
  float* w_hhT = ws + OFF_WHHT;
  float* xpart = ws + OFF_XPART;
  float* hcat = ws + OFF_HCAT;
  float* hG = ws + OFF_HG;
  int* flags = (int*)(ws + OFF_CTR);

  float* em = (float*)d_out;
  float* d_loss = em + NB * NT * NL;
  float* preds = d_loss + 1;

  prep<<<8192, 256, 0, stream>>>(w_ih_f, w_ih_b, w_hh_f, w_hh_b, w_ihT, w_hhT, d_loss, flags);
  gemm_x<<<dim3(16, 128), 256, 0, stream>>>(seq_out, w_ihT, b_f, b_b, xpart);
  lstm_scan<<<64, 256, 0, stream>>>(w_hhT, xpart, hcat, hG, flags);
  emissions<<<4096, 256, 0, stream>>>(hcat, w_tag, b_tag, em);
  crf_fwd<<<32, 64, 0, stream>>>(em, attn, labels, start_t, end_t, trans, d_loss);
  crf_viterbi<<<32, 64, 0, stream>>>(em, attn, start_t, end_t, trans, preds);
}

// Round 8
// 5850.621 us; speedup vs baseline: 1.9955x; 1.0970x over previous
//
#include <hip/hip_runtime.h>
#include <cmath>

// ---------------------------------------------------------------------------
// BertBiLSTMCRF round 8 = round 7 hardened (round 7 died in-container; prime
// suspect was the inline-asm dwordx4 readback -> replaced with the proven 8B
// __hip_atomic_load path; poll timeout 50ms -> ~2ms so a broken sync fails
// correctness instead of killing the container).
// Structure: 32 blocks x 512 threads; block m owns hidden units [8m,8m+8) for
// BOTH directions. Per step: F-partials -> F-update/publish -> flagF ->
// B-partials -> B-update/publish -> flagB -> pollF -> readbackF -> pollB ->
// readbackB (F flag latency hides under B compute). Parity double-buffered hG
// (race-free by round-4 induction). Pure fp32 numerics (validated r2-r6).
// ---------------------------------------------------------------------------

#define NB 32
#define NT 512
#define ND 768
#define NH 256
#define NG 1024   // 4*NH
#define NC 2048   // 2*NG
#define NL 9
#define NHC 512   // 2*NH
#define PPD 32    // participating blocks
#define HPAD 260  // padded row stride for hS rows (260%32=4 -> conflict-free)
#define HSZ  (32 * HPAD)
#define NBUF (2 * NB * NH)   // one parity buffer: [2 dirs][32 m][32 b][8 u]

typedef float f32x4 __attribute__((ext_vector_type(4)));

static const size_t OFF_WIHT  = 0;                       // 1572864 floats
static const size_t OFF_WHHT  = 1572864;                 // 524288
static const size_t OFF_XPART = 2097152;                 // 33554432
static const size_t OFF_HCAT  = 35651584;                // 8388608
static const size_t OFF_HG    = 44040192;                // 32768
static const size_t OFF_CTR   = 44072960;                // 1024 ints (flags)

// ---------------------------------------------------------------- prep ------
__global__ void prep(const float* __restrict__ wihf, const float* __restrict__ wihb,
                     const float* __restrict__ whhf, const float* __restrict__ whhb,
                     float* __restrict__ w_ihT, float* __restrict__ w_hhT,
                     float* __restrict__ d_loss, int* __restrict__ flags) {
  int idx = blockIdx.x * 256 + threadIdx.x;
  if (idx == 0) d_loss[0] = 0.f;
  if (idx < 1024) flags[idx] = 0;
  if (idx < 1572864) {
    int k = idx >> 11;
    int c = idx & 2047;
    int d = c >> 10;
    int j = c & 1023;
    w_ihT[idx] = d ? wihb[j * ND + k] : wihf[j * ND + k];
  } else {
    int i2 = idx - 1572864;
    int d = i2 >> 18;
    int r = i2 & 262143;
    int k = r >> 10;
    int j = r & 1023;
    w_hhT[i2] = d ? whhb[j * NH + k] : whhf[j * NH + k];
  }
}

// -------------------------------------------------------------- gemm_x ------
__global__ __launch_bounds__(256, 2)
void gemm_x(const float* __restrict__ x, const float* __restrict__ wT,
            const float* __restrict__ bf, const float* __restrict__ bb,
            float* __restrict__ xpart) {
  __shared__ float As[8][128];
  __shared__ float Bs[8][128];
  const int tid = threadIdx.x;
  const int tx = tid & 15, ty = tid >> 4;
  const int r0 = blockIdx.y * 128, c0 = blockIdx.x * 128;

  float acc[8][8] = {};

  const int arow = tid >> 1;
  const int akq  = (tid & 1) * 4;
  const int rA = r0 + arow;
  const float* aptr = x + ((size_t)((rA & 31) * NT + (rA >> 5)) * ND) + akq;
  const int bk = tid >> 5;
  const int bc = (tid & 31) * 4;
  const float* bptr = wT + (size_t)bk * NC + c0 + bc;

  for (int k0 = 0; k0 < ND; k0 += 8) {
    float4 av = *(const float4*)(aptr + k0);
    float4 bv = *(const float4*)(bptr + (size_t)k0 * NC);
    __syncthreads();
    As[akq + 0][arow] = av.x;
    As[akq + 1][arow] = av.y;
    As[akq + 2][arow] = av.z;
    As[akq + 3][arow] = av.w;
    *(float4*)&Bs[bk][bc] = bv;
    __syncthreads();
#pragma unroll
    for (int k = 0; k < 8; ++k) {
      float4 a0 = *(const float4*)&As[k][ty * 8];
      float4 a1 = *(const float4*)&As[k][ty * 8 + 4];
      float4 b0 = *(const float4*)&Bs[k][tx * 8];
      float4 b1 = *(const float4*)&Bs[k][tx * 8 + 4];
      float am[8] = {a0.x, a0.y, a0.z, a0.w, a1.x, a1.y, a1.z, a1.w};
      float bm[8] = {b0.x, b0.y, b0.z, b0.w, b1.x, b1.y, b1.z, b1.w};
#pragma unroll
      for (int i = 0; i < 8; ++i)
#pragma unroll
        for (int j = 0; j < 8; ++j) acc[i][j] += am[i] * bm[j];
    }
  }

  const int cbase = c0 + tx * 8;
  float bias[8];
#pragma unroll
  for (int j = 0; j < 8; ++j) {
    int c = cbase + j;
    bias[j] = (c < NG) ? bf[c] : bb[c - NG];
  }
#pragma unroll
  for (int i = 0; i < 8; ++i) {
    int r = r0 + ty * 8 + i;
    float4 v0 = {acc[i][0] + bias[0], acc[i][1] + bias[1],
                 acc[i][2] + bias[2], acc[i][3] + bias[3]};
    float4 v1 = {acc[i][4] + bias[4], acc[i][5] + bias[5],
                 acc[i][6] + bias[6], acc[i][7] + bias[7]};
    *(float4*)(xpart + (size_t)r * NC + cbase) = v0;
    *(float4*)(xpart + (size_t)r * NC + cbase + 4) = v1;
  }
}

// ------------------------------------------------------------ lstm_scan -----
__global__ __launch_bounds__(512, 1)
void lstm_scan(const float* __restrict__ whhT, const float* __restrict__ xpart,
               float* __restrict__ hcat, float* __restrict__ hG,
               int* __restrict__ flags) {
  __shared__ float wS[2 * 256 * 32];   // [d][k][l] 64KB
  __shared__ float hS[2 * HSZ];        // [d][b][k] padded, 65KB
  __shared__ float pSw[32 * 68];       // [b][(pcg*2+kh)*4+j] 8.5KB
  const int tid = threadIdx.x;
  const int m = blockIdx.x;

  // one-time weight load: wS[d][k][l], l=pcg*4+j <-> col (l>>3)*256+m*8+(l&7)
  for (int dd = 0; dd < 2; ++dd) {
    const float* wsrc = whhT + (size_t)dd * NH * NG;
    for (int it = 0; it < 16; ++it) {
      int i = it * 512 + tid;          // 0..8191
      int k = i >> 5, l = i & 31;
      int g = l >> 3, u2 = l & 7;
      wS[(dd * 256 + k) * 32 + l] = wsrc[(size_t)k * NG + g * 256 + m * 8 + u2];
    }
  }
  for (int i = tid; i < 2 * HSZ; i += 512) hS[i] = 0.f;
  __syncthreads();

  // roles
  const int kh = tid >> 8;             // 0/1 : k-half for partials
  const int pr = tid & 255;
  const int pb = pr >> 3;              // batch for partials
  const int pcg = pr & 7;              // col-group (4 cols)
  const int l0 = pcg * 4;
  const int ub = tid >> 3;             // batch for update (tid<256)
  const int uu = tid & 7;              // unit for update
  const int c0i = (uu >> 2) * 8 + (uu & 3);

  float cf = 0.f, cb = 0.f;

  for (int s = 0; s < NT; ++s) {
    const int tf = s, tb = NT - 1 - s;

    // prefetch x-parts for both dirs (update threads)
    float xf[4], xb[4];
    if (tid < 256) {
      const float* xpf = xpart + ((size_t)(tf * NB + ub) * NC) + m * 8 + uu;
      const float* xpb = xpart + ((size_t)(tb * NB + ub) * NC) + NG + m * 8 + uu;
#pragma unroll
      for (int g = 0; g < 4; ++g) { xf[g] = xpf[g * 256]; xb[g] = xpb[g * 256]; }
    }

    for (int d = 0; d < 2; ++d) {
      // ---- gate partials (all 512 threads, k-split) ----
      const float* hrow = hS + d * HSZ + pb * HPAD + kh * 128;
      const float* wcol = wS + (size_t)(d * 256 + kh * 128) * 32 + l0;
      f32x4 acc = {0.f, 0.f, 0.f, 0.f};
#pragma unroll 4
      for (int kk = 0; kk < 128; kk += 4) {
        f32x4 hv = *(const f32x4*)(hrow + kk);
        f32x4 w0 = *(const f32x4*)(wcol + (size_t)(kk + 0) * 32);
        f32x4 w1 = *(const f32x4*)(wcol + (size_t)(kk + 1) * 32);
        f32x4 w2 = *(const f32x4*)(wcol + (size_t)(kk + 2) * 32);
        f32x4 w3 = *(const f32x4*)(wcol + (size_t)(kk + 3) * 32);
        acc += hv.x * w0;
        acc += hv.y * w1;
        acc += hv.z * w2;
        acc += hv.w * w3;
      }
      *(f32x4*)(pSw + pb * 68 + (pcg * 2 + kh) * 4) = acc;
      __syncthreads();

      // ---- combine + update + publish (threads 0..255) ----
      if (tid < 256) {
        const float* pS = pSw + ub * 68;
        const float* xv = d ? xb : xf;
        float g0 = pS[c0i]      + pS[c0i + 4]  + xv[0];
        float g1 = pS[c0i + 16] + pS[c0i + 20] + xv[1];
        float g2 = pS[c0i + 32] + pS[c0i + 36] + xv[2];
        float g3 = pS[c0i + 48] + pS[c0i + 52] + xv[3];
        float ii = 1.f / (1.f + expf(-g0));
        float ff = 1.f / (1.f + expf(-g1));
        float tg = tanhf(g2);
        float oo = 1.f / (1.f + expf(-g3));
        float& cc = d ? cb : cf;
        cc = ff * cc + ii * tg;
        float h = oo * tanhf(cc);
        const int t = d ? tb : tf;
        hcat[((size_t)(ub * NT + t)) * NHC + d * NH + m * 8 + uu] = h;
        float* dst = hG + ((s & 1) ? NBUF : 0) + d * 8192 + m * 256 + ub * 8 + uu;
        __hip_atomic_store(dst, h, __ATOMIC_RELAXED, __HIP_MEMORY_SCOPE_AGENT);
      }
      __syncthreads();    // drains publishing waves' stores before flag
      if (tid == 0)
        __hip_atomic_store(&flags[d * 32 + m], s + 1, __ATOMIC_RELEASE,
                           __HIP_MEMORY_SCOPE_AGENT);
    }

    // ---- poll + readback (skip after the last step) ----
    if (s < NT - 1) {
      const float* bufpar = hG + ((s & 1) ? NBUF : 0);
      for (int d = 0; d < 2; ++d) {
        if (tid < 64) {
          int* fl = flags + d * 32;
          long long t0 = wall_clock64();
          for (;;) {
            int v = (tid < 32)
                ? __hip_atomic_load(&fl[tid], __ATOMIC_RELAXED,
                                    __HIP_MEMORY_SCOPE_AGENT)
                : 0x7fffffff;
            if (__ballot(v > s) == ~0ULL) break;
            if (wall_clock64() - t0 > 200000LL) break;  // ~2ms hang guard
          }
        }
        __syncthreads();
        // readback: 8x 8B bypass loads per thread (proven path from r5/r6)
        const unsigned long long* src = (const unsigned long long*)
            (bufpar + d * 8192);
        unsigned long long vv[8];
#pragma unroll
        for (int i = 0; i < 8; ++i)
          vv[i] = __hip_atomic_load(&src[i * 512 + tid], __ATOMIC_RELAXED,
                                    __HIP_MEMORY_SCOPE_AGENT);
        float* hd = hS + d * HSZ;
#pragma unroll
        for (int i = 0; i < 8; ++i) {
          int f = i * 512 + tid;            // float2 index 0..4095
          union { unsigned long long uu; float ff2[2]; } cv;
          cv.uu = vv[i];
          int mq = f >> 7;
          int r = f & 127;
          int bb = r >> 2;
          int u2 = (r & 3) * 2;
          hd[bb * HPAD + mq * 8 + u2] = cv.ff2[0];
          hd[bb * HPAD + mq * 8 + u2 + 1] = cv.ff2[1];
        }
        if (d == 0) __syncthreads();   // hS[0] ready before next F-partials;
                                       // hS[1] ordered by next F-phase barrier
      }
    }
  }
}

// ------------------------------------------------------------ emissions -----
__global__ void emissions(const float* __restrict__ hcat, const float* __restrict__ wtag,
                          const float* __restrict__ btag, float* __restrict__ em) {
  __shared__ float wS[NL * NHC];
  const int tid = threadIdx.x;
  for (int i = tid; i < NL * NHC; i += 256) wS[i] = wtag[i];
  __syncthreads();
  const int w = tid >> 6, l = tid & 63;
  const int r = blockIdx.x * 4 + w;
  const float* hp = hcat + (size_t)r * NHC;
  float acc[NL] = {};
#pragma unroll
  for (int rep = 0; rep < 8; ++rep) {
    float hv = hp[l + rep * 64];
#pragma unroll
    for (int j = 0; j < NL; ++j) acc[j] += hv * wS[j * NHC + l + rep * 64];
  }
#pragma unroll
  for (int j = 0; j < NL; ++j) {
#pragma unroll
    for (int off = 32; off; off >>= 1) acc[j] += __shfl_xor(acc[j], off, 64);
  }
  if (l == 0) {
#pragma unroll
    for (int j = 0; j < NL; ++j) em[(size_t)r * NL + j] = acc[j] + btag[j];
  }
}

// -------------------------------------------------------------- crf_fwd -----
__global__ void crf_fwd(const float* __restrict__ em, const int* __restrict__ mask,
                        const int* __restrict__ labels, const float* __restrict__ start,
                        const float* __restrict__ endt, const float* __restrict__ trans,
                        float* __restrict__ d_loss) {
  __shared__ float emS[NT * NL];
  __shared__ float maskS[NT];
  __shared__ int lblS[NT];
  const int b = blockIdx.x;
  const int tid = threadIdx.x;
  for (int i = tid; i < NT * NL; i += 64) emS[i] = em[(size_t)b * NT * NL + i];
  for (int i = tid; i < NT; i += 64) {
    maskS[i] = (float)mask[b * NT + i];
    int lb = labels[b * NT + i];
    lblS[i] = (lb == -100) ? 0 : lb;
  }
  __syncthreads();

  float part = 0.f, msum = 0.f;
  for (int t = tid; t < NT; t += 64) {
    msum += maskS[t];
    if (t >= 1)
      part += (trans[lblS[t - 1] * NL + lblS[t]] + emS[t * NL + lblS[t]]) * maskS[t];
  }
#pragma unroll
  for (int off = 32; off; off >>= 1) {
    part += __shfl_xor(part, off, 64);
    msum += __shfl_xor(msum, off, 64);
  }

  const int j = tid >> 2, q = tid & 3;
  const bool leader = (q == 0) && (j < NL);
  float tr0 = 0.f, tr1 = 0.f, tr2 = -1e30f;
  float score = 0.f;
  if (tid < 36) {
    tr0 = trans[q * NL + j];
    tr1 = trans[(q + 4) * NL + j];
    if (q == 0) tr2 = trans[8 * NL + j];
    if (leader) score = start[j] + emS[j];
  }
  for (int t = 1; t < NT; ++t) {
    float s0 = __shfl(score, q * 4, 64);
    float s1 = __shfl(score, (q + 4) * 4, 64);
    float s2 = __shfl(score, 32, 64);
    float v0 = s0 + tr0, v1 = s1 + tr1;
    float v2 = (q == 0) ? (s2 + tr2) : -1e30f;
    float m = fmaxf(fmaxf(v0, v1), v2);
    m = fmaxf(m, __shfl_xor(m, 1, 4));
    m = fmaxf(m, __shfl_xor(m, 2, 4));
    float e = expf(v0 - m) + expf(v1 - m) + ((q == 0) ? expf(v2 - m) : 0.f);
    e += __shfl_xor(e, 1, 4);
    e += __shfl_xor(e, 2, 4);
    if (leader) {
      float nxt = m + logf(e) + emS[t * NL + j];
      score = (maskS[t] > 0.f) ? nxt : score;
    }
  }
  float vs[NL];
  float mx = -1e30f;
#pragma unroll
  for (int jj = 0; jj < NL; ++jj) {
    float sj = __shfl(score, jj * 4, 64) + endt[jj];
    vs[jj] = sj;
    mx = fmaxf(mx, sj);
  }
  float se = 0.f;
#pragma unroll
  for (int jj = 0; jj < NL; ++jj) se += expf(vs[jj] - mx);
  float denom = mx + logf(se);
  if (tid == 0) {
    int li = (int)(msum - 0.5f);
    float num = start[lblS[0]] + emS[lblS[0]] + part + endt[lblS[li]];
    atomicAdd(d_loss, -(num - denom) * (1.f / 32.f));
  }
}

// ---------------------------------------------------------- crf_viterbi -----
__global__ void crf_viterbi(const float* __restrict__ em, const int* __restrict__ mask,
                            const float* __restrict__ start, const float* __restrict__ endt,
                            const float* __restrict__ trans, float* __restrict__ preds) {
  __shared__ float emS[NT * NL];
  __shared__ int maskS[NT];
  __shared__ short bpS[(NT - 1) * NL];
  __shared__ short tagS[NT];
  const int b = blockIdx.x;
  const int tid = threadIdx.x;
  for (int i = tid; i < NT * NL; i += 64) emS[i] = em[(size_t)b * NT * NL + i];
  for (int i = tid; i < NT; i += 64) maskS[i] = mask[b * NT + i];
  __syncthreads();

  const int j = tid >> 2, q = tid & 3;
  const bool leader = (q == 0) && (j < NL);
  float tr0 = 0.f, tr1 = 0.f, tr2 = -1e30f;
  float score = 0.f;
  if (tid < 36) {
    tr0 = trans[q * NL + j];
    tr1 = trans[(q + 4) * NL + j];
    if (q == 0) tr2 = trans[8 * NL + j];
    if (leader) score = start[j] + emS[j];
  }
  for (int t = 1; t < NT; ++t) {
    float s0 = __shfl(score, q * 4, 64);
    float s1 = __shfl(score, (q + 4) * 4, 64);
    float s2 = __shfl(score, 32, 64);
    float v0 = s0 + tr0, v1 = s1 + tr1;
    float v2 = (q == 0) ? (s2 + tr2) : -1e30f;
    float bv = v0;
    int bi = q;
    if (v1 > bv) { bv = v1; bi = q + 4; }
    if (q == 0 && v2 > bv) { bv = v2; bi = 8; }
#pragma unroll
    for (int off = 1; off <= 2; off <<= 1) {
      float ov = __shfl_xor(bv, off, 4);
      int oi = __shfl_xor(bi, off, 4);
      if (ov > bv || (ov == bv && oi < bi)) { bv = ov; bi = oi; }
    }
    if (leader) {
      int keep = maskS[t];
      float nxt = bv + emS[t * NL + j];
      bpS[(t - 1) * NL + j] = keep ? (short)bi : (short)j;
      score = keep ? nxt : score;
    }
  }
  float fv[NL];
#pragma unroll
  for (int jj = 0; jj < NL; ++jj) fv[jj] = __shfl(score, jj * 4, 64) + endt[jj];
  if (tid == 0) {
    int last = 0;
    float bvv = fv[0];
#pragma unroll
    for (int jj = 1; jj < NL; ++jj)
      if (fv[jj] > bvv) { bvv = fv[jj]; last = jj; }
    tagS[NT - 1] = (short)last;
    for (int t = NT - 1; t >= 1; --t) tagS[t - 1] = bpS[(t - 1) * NL + tagS[t]];
  }
  __syncthreads();
  for (int i = tid; i < NT; i += 64) preds[(size_t)b * NT + i] = (float)tagS[i];
}

// ---------------------------------------------------------------------------
extern "C" void kernel_launch(void* const* d_in, const int* in_sizes, int n_in,
                              void* d_out, int out_size, void* d_ws, size_t ws_size,
                              hipStream_t stream) {
  const float* seq_out = (const float*)d_in[0];
  const int* attn = (const int*)d_in[1];
  const int* labels = (const int*)d_in[2];
  const float* w_ih_f = (const float*)d_in[3];
  const float* w_hh_f = (const float*)d_in[4];
  const float* b_f = (const float*)d_in[5];
  const float* w_ih_b = (const float*)d_in[6];
  const float* w_hh_b = (const float*)d_in[7];
  const float* b_b = (const float*)d_in[8];
  const float* w_tag = (const float*)d_in[9];
  const float* b_tag = (const float*)d_in[10];
  const float* start_t = (const float*)d_in[11];
  const float* end_t = (const float*)d_in[12];
  const float* trans = (const float*)d_in[13];
  (void)in_sizes; (void)n_in; (void)out_size; (void)ws_size;

  float* ws = (float*)d_ws;
  float* w_ihT = ws + OFF_WIHT;
  float* w_hhT = ws + OFF_WHHT;
  float* xpart = ws + OFF_XPART;
  float* hcat = ws + OFF_HCAT;
  float* hG = ws + OFF_HG;
  int* flags = (int*)(ws + OFF_CTR);

  float* em = (float*)d_out;
  float* d_loss = em + NB * NT * NL;
  float* preds = d_loss + 1;

  prep<<<8192, 256, 0, stream>>>(w_ih_f, w_ih_b, w_hh_f, w_hh_b, w_ihT, w_hhT, d_loss, flags);
  gemm_x<<<dim3(16, 128), 256, 0, stream>>>(seq_out, w_ihT, b_f, b_b, xpart);
  lstm_scan<<<32, 512, 0, stream>>>(w_hhT, xpart, hcat, hG, flags);
  emissions<<<4096, 256, 0, stream>>>(hcat, w_tag, b_tag, em);
  crf_fwd<<<32, 64, 0, stream>>>(em, attn, labels, start_t, end_t, trans, d_loss);
  crf_viterbi<<<32, 64, 0, stream>>>(em, attn, start_t, end_t, trans, preds);
}